// Round 6
// baseline (133.735 us; speedup 1.0000x reference)
//
#include <hip/hip_runtime.h>

namespace {
constexpr int B = 8, C = 64, H = 128, W = 128;
constexpr int HW  = H * W;
constexpr int CHW = C * HW;
}

// ---------------- K1: 4-px-vectorized affinity + softmax -> aff[pix][8] (AoS) ----------------
// Block: 256 thr = 32 w-chunks x 8 channel-groups (8 ch each). Grid: (H, B).
__global__ __launch_bounds__(256) void aff_kernel(const float* __restrict__ xs,
                                                  float* __restrict__ aff)
{
    __shared__ float part[8][32][33];   // stride 33 -> conflict-free

    const int t  = threadIdx.x;
    const int ck = t & 31;              // w-chunk: w4 = ck*4
    const int cg = t >> 5;              // channel group 0..7
    const int h  = blockIdx.x;
    const int b  = blockIdx.y;
    const int w4 = ck * 4;

    const bool ft = (h == 0), fb = (h == H - 1), fl = (ck == 0), fr = (ck == 31);
    const int oT = ft ? 0 : -W;         // clamped row offsets (values zeroed below)
    const int oB = fb ? 0 :  W;
    const int oL = fl ? 0 : -1;         // clamped col offsets for edge scalars
    const int oR = fr ? 3 :  4;

    const float* base = xs + (size_t)b * CHW + (size_t)cg * 8 * HW + h * W + w4;

    float p[4][8];
#pragma unroll
    for (int i = 0; i < 4; ++i)
#pragma unroll
        for (int k = 0; k < 8; ++k) p[i][k] = 0.f;

#pragma unroll
    for (int c = 0; c < 8; ++c) {
        const float* pc = base + (size_t)c * HW;
        float4 m4 = *(const float4*)pc;
        float4 t4 = *(const float4*)(pc + oT);
        float4 b4 = *(const float4*)(pc + oB);
        float tl = pc[oT + oL], tr = pc[oT + oR];
        float ml = pc[oL],      mr = pc[oR];
        float bl = pc[oB + oL], br = pc[oB + oR];
        if (ft) { t4.x = t4.y = t4.z = t4.w = 0.f; tl = 0.f; tr = 0.f; }
        if (fb) { b4.x = b4.y = b4.z = b4.w = 0.f; bl = 0.f; br = 0.f; }
        if (fl) { tl = 0.f; ml = 0.f; bl = 0.f; }
        if (fr) { tr = 0.f; mr = 0.f; br = 0.f; }
        const float T[6] = {tl, t4.x, t4.y, t4.z, t4.w, tr};
        const float M[6] = {ml, m4.x, m4.y, m4.z, m4.w, mr};
        const float Bo[6]= {bl, b4.x, b4.y, b4.z, b4.w, br};
        const float ce[4]= {m4.x, m4.y, m4.z, m4.w};
#pragma unroll
        for (int i = 0; i < 4; ++i) {
            p[i][0] = fmaf(ce[i], T[i],      p[i][0]);
            p[i][1] = fmaf(ce[i], T[i + 1],  p[i][1]);
            p[i][2] = fmaf(ce[i], T[i + 2],  p[i][2]);
            p[i][3] = fmaf(ce[i], M[i],      p[i][3]);
            p[i][4] = fmaf(ce[i], M[i + 2],  p[i][4]);
            p[i][5] = fmaf(ce[i], Bo[i],     p[i][5]);
            p[i][6] = fmaf(ce[i], Bo[i + 1], p[i][6]);
            p[i][7] = fmaf(ce[i], Bo[i + 2], p[i][7]);
        }
    }

#pragma unroll
    for (int i = 0; i < 4; ++i)
#pragma unroll
        for (int k = 0; k < 8; ++k) part[cg][ck][i * 8 + k] = p[i][k];
    __syncthreads();

    // Reduce over 8 channel groups + softmax; threads 0..127 each own pixel w = t.
    if (t < 128) {
        const int c2 = t >> 2, px = t & 3;   // w = c2*4 + px = t
        float v[8];
#pragma unroll
        for (int k = 0; k < 8; ++k) {
            float s = 0.f;
#pragma unroll
            for (int g = 0; g < 8; ++g) s += part[g][c2][px * 8 + k];
            v[k] = s;
        }
        float m = v[0];
#pragma unroll
        for (int k = 1; k < 8; ++k) m = fmaxf(m, v[k]);
        float s = 0.f;
#pragma unroll
        for (int k = 0; k < 8; ++k) { v[k] = __expf(v[k] - m); s += v[k]; }
        const float inv = 1.f / s;
        float* pa = aff + ((size_t)b * HW + h * W + t) * 8;
        *(float4*)pa       = make_float4(v[0] * inv, v[1] * inv, v[2] * inv, v[3] * inv);
        *(float4*)(pa + 4) = make_float4(v[4] * inv, v[5] * inv, v[6] * inv, v[7] * inv);
    }
}

// ---------------- K2: 4 px x 4 ch per thread; values zeroed at edges ----------------
// Block: 256 thr = 32 w-chunks x 8 channel-slots (4 ch each). Grid: (C/32, H, B).
__global__ __launch_bounds__(256) void apply_kernel(const float* __restrict__ xx,
                                                    const float* __restrict__ aff,
                                                    float* __restrict__ out)
{
    const int t  = threadIdx.x;
    const int ck = t & 31;
    const int cs = t >> 5;
    const int h  = blockIdx.y;
    const int b  = blockIdx.z;
    const int c0 = blockIdx.x * 32 + cs * 4;
    const int w4 = ck * 4;

    const bool ft = (h == 0), fb = (h == H - 1), fl = (ck == 0), fr = (ck == 31);
    const int oT = ft ? 0 : -W;
    const int oB = fb ? 0 :  W;
    const int oL = fl ? 0 : -1;
    const int oR = fr ? 3 :  4;

    // per-pixel softmax weights a[px][k]
    const float* pa = aff + ((size_t)b * HW + h * W + w4) * 8;
    float a[4][8];
#pragma unroll
    for (int i = 0; i < 4; ++i) {
        const float4 lo = *(const float4*)(pa + i * 8);
        const float4 hi = *(const float4*)(pa + i * 8 + 4);
        a[i][0] = lo.x; a[i][1] = lo.y; a[i][2] = lo.z; a[i][3] = lo.w;
        a[i][4] = hi.x; a[i][5] = hi.y; a[i][6] = hi.z; a[i][7] = hi.w;
    }

    const float* pxb = xx  + (size_t)b * CHW + (size_t)c0 * HW + h * W + w4;
    float*       pob = out + (size_t)b * CHW + (size_t)c0 * HW + h * W + w4;
#pragma unroll
    for (int c = 0; c < 4; ++c) {
        const float* pc = pxb + (size_t)c * HW;
        float4 m4 = *(const float4*)pc;
        float4 t4 = *(const float4*)(pc + oT);
        float4 b4 = *(const float4*)(pc + oB);
        float tl = pc[oT + oL], tr = pc[oT + oR];
        float ml = pc[oL],      mr = pc[oR];
        float bl = pc[oB + oL], br = pc[oB + oR];
        if (ft) { t4.x = t4.y = t4.z = t4.w = 0.f; tl = 0.f; tr = 0.f; }
        if (fb) { b4.x = b4.y = b4.z = b4.w = 0.f; bl = 0.f; br = 0.f; }
        if (fl) { tl = 0.f; ml = 0.f; bl = 0.f; }
        if (fr) { tr = 0.f; mr = 0.f; br = 0.f; }
        const float T[6] = {tl, t4.x, t4.y, t4.z, t4.w, tr};
        const float M[6] = {ml, m4.x, m4.y, m4.z, m4.w, mr};
        const float Bo[6]= {bl, b4.x, b4.y, b4.z, b4.w, br};
        float r[4];
#pragma unroll
        for (int i = 0; i < 4; ++i) {
            float acc = a[i][0] * T[i];
            acc = fmaf(a[i][1], T[i + 1],  acc);
            acc = fmaf(a[i][2], T[i + 2],  acc);
            acc = fmaf(a[i][3], M[i],      acc);
            acc = fmaf(a[i][4], M[i + 2],  acc);
            acc = fmaf(a[i][5], Bo[i],     acc);
            acc = fmaf(a[i][6], Bo[i + 1], acc);
            acc = fmaf(a[i][7], Bo[i + 2], acc);
            r[i] = acc;
        }
        *(float4*)(pob + (size_t)c * HW) = make_float4(r[0], r[1], r[2], r[3]);
    }
}

extern "C" void kernel_launch(void* const* d_in, const int* in_sizes, int n_in,
                              void* d_out, int out_size, void* d_ws, size_t ws_size,
                              hipStream_t stream) {
    const float* xs = (const float*)d_in[0];   // x_stem
    const float* xx = (const float*)d_in[1];   // x
    float* out = (float*)d_out;
    float* aff = (float*)d_ws;                 // 8*B*HW floats = 4 MiB

    aff_kernel<<<dim3(H, B), 256, 0, stream>>>(xs, aff);
    apply_kernel<<<dim3(C / 32, H, B), 256, 0, stream>>>(xx, aff, out);
}